// Round 18
// baseline (105.452 us; speedup 1.0000x reference)
//
#include <hip/hip_runtime.h>
#include <math.h>
#include <stdint.h>

#define KK 5
#define PADK 2
#define C_IN 8
#define O_OUT 8
#define HH 512
#define WW 512
#define TH 8
#define TW 128
#define CH 4                      // channels per staged half
#define LROWS 12                  // TH + 4
#define LCOLS 136                 // TW + 4 halo, padded (f32 cols)
#define WSTR 12                   // dwords per (c,og,dy) chunk: 10 used
#define NW (O_OUT * C_IN * KK * KK)   // 1600
#define XHALF (CH * LROWS * (LCOLS / 2))   // float2 slots per half = 3264

// Full-rate VOP3 3-input max.
static __device__ __forceinline__ float max3f(float a, float b, float c) {
    float d;
    asm("v_max3_f32 %0, %1, %2, %3" : "=v"(d) : "v"(a), "v"(b), "v"(c));
    return d;
}

// Packed f32 add with src0 BROADCAST via VOP3P op_sel:
//   PK_LO: dst = (x.lo + w.lo, x.lo + w.hi)   -- one tap vs two o's
//   PK_HI: dst = (x.hi + w.lo, x.hi + w.hi)
#define PK_LO(dst, xp, wp)                                                  \
    asm("v_pk_add_f32 %0, %1, %2 op_sel:[0,0] op_sel_hi:[0,1]"              \
        : "=v"(dst) : "v"(xp), "v"(wp))
#define PK_HI(dst, xp, wp)                                                  \
    asm("v_pk_add_f32 %0, %1, %2 op_sel:[1,0] op_sel_hi:[1,1]"              \
        : "=v"(dst) : "v"(xp), "v"(wp))

__global__ __launch_bounds__(512, 8)
void dil_kernel(const float* __restrict__ x,
                const float* __restrict__ wf,
                float* __restrict__ out) {
    __shared__ __align__(16) float xlds[CH][LROWS][LCOLS];      // 26,112 B
    __shared__ __align__(16) float wlds[C_IN * 4 * KK * WSTR];  //  7,680 B

    const int tid = threadIdx.x;
    const int w0 = blockIdx.x * TW;
    const int h0 = blockIdx.y * TH;
    const int n  = blockIdx.z;
    const float* xn = x + (size_t)n * (C_IN * HH * WW);

    const int l   = tid & 63;
    const int wid = tid >> 6;
    const int og  = wid & 3;
    const int rbase = (wid >> 2) * 4;

    const float* xbase = &xlds[0][rbase][2 * l];
    const float* wog   = wlds + og * (KK * WSTR);

    float acc[2][4][2];           // [o2][j][pixel]
    #pragma unroll
    for (int a = 0; a < 2; ++a)
        #pragma unroll
        for (int j = 0; j < 4; ++j) {
            acc[a][j][0] = -INFINITY;
            acc[a][j][1] = -INFINITY;
        }

    for (int h = 0; h < 2; ++h) {
        if (h) __syncthreads();

        // ---- stage x half (4 channels), zero halo == reference zero pad ----
        for (int idx = tid; idx < XHALF; idx += 512) {
            int cc  = idx / (LROWS * (LCOLS / 2));
            int rem = idx - cc * (LROWS * (LCOLS / 2));
            int r   = rem / (LCOLS / 2);
            int jp  = rem - r * (LCOLS / 2);
            int gh = h0 - PADK + r;
            int gw = w0 - PADK + 2 * jp;
            float v0 = 0.f, v1 = 0.f;
            if ((unsigned)gh < (unsigned)HH) {
                const float* row = xn + ((size_t)(h * CH + cc) * HH + gh) * WW;
                if ((unsigned)gw < (unsigned)WW) v0 = row[gw];
                if ((unsigned)(gw + 1) < (unsigned)WW) v1 = row[gw + 1];
            }
            *(float2*)&xlds[cc][r][2 * jp] = make_float2(v0, v1);
        }
        // ---- stage weights once: [c][g][dy] -> 5 dx-major o-PAIRS:
        //      chunk dword (dx*2 + o2) = w[(2g+o2), c, dy, dx] ----
        if (h == 0) {
            for (int t = tid; t < NW; t += 512) {
                int dx = t % KK;  int q = t / KK;
                int o2 = q & 1;   q >>= 1;
                int dy = q % KK;  q /= KK;
                int g  = q & 3;   int c = q >> 2;
                int o = g * 2 + o2;
                wlds[((c * 4 + g) * KK + dy) * WSTR + dx * 2 + o2] =
                    wf[((o * C_IN + c) * KK + dy) * KK + dx];
            }
        }
        __syncthreads();

        const float* wh = wog + h * (CH * 4 * KK * WSTR);

        #pragma unroll
        for (int cc = 0; cc < CH; ++cc) {
            #pragma unroll
            for (int dy = 0; dy < KK; ++dy) {
                const float* wch = wh + (cc * 4 * KK + dy) * WSTR;
                float4 wa = *(const float4*)(wch);      // W0=(x,y) W1=(z,w)
                float4 wb = *(const float4*)(wch + 4);  // W2=(x,y) W3=(z,w)
                float2 W4 = *(const float2*)(wch + 8);
                float2 W0 = make_float2(wa.x, wa.y);
                float2 W1 = make_float2(wa.z, wa.w);
                float2 W2 = make_float2(wb.x, wb.y);
                float2 W3 = make_float2(wb.z, wb.w);
                #pragma unroll
                for (int j = 0; j < 4; ++j) {
                    const float* lr = xbase + cc * (LROWS * LCOLS)
                                            + (dy + j) * LCOLS;
                    float2 A = *(const float2*)(lr);        // (u0,u1)
                    float2 B = *(const float2*)(lr + 2);    // (u2,u3)
                    float2 D = *(const float2*)(lr + 4);    // (u4,u5)

                    float2 T0, T1, T2, T3, T4;   // pixel0 taps, (oA,oB) packed
                    PK_LO(T0, A, W0);            // u0 + (wA0,wB0)
                    PK_HI(T1, A, W1);            // u1 + (wA1,wB1)
                    PK_LO(T2, B, W2);            // u2
                    PK_HI(T3, B, W3);            // u3
                    PK_LO(T4, D, W4);            // u4
                    float2 S0, S1, S2, S3, S4;   // pixel1 taps
                    PK_HI(S0, A, W0);            // u1
                    PK_LO(S1, B, W1);            // u2
                    PK_HI(S2, B, W2);            // u3
                    PK_LO(S3, D, W3);            // u4
                    PK_HI(S4, D, W4);            // u5

                    acc[0][j][0] = max3f(acc[0][j][0],
                                         max3f(T0.x, T1.x, T2.x),
                                         fmaxf(T3.x, T4.x));
                    acc[1][j][0] = max3f(acc[1][j][0],
                                         max3f(T0.y, T1.y, T2.y),
                                         fmaxf(T3.y, T4.y));
                    acc[0][j][1] = max3f(acc[0][j][1],
                                         max3f(S0.x, S1.x, S2.x),
                                         fmaxf(S3.x, S4.x));
                    acc[1][j][1] = max3f(acc[1][j][1],
                                         max3f(S0.y, S1.y, S2.y),
                                         fmaxf(S3.y, S4.y));
                }
            }
        }
    }

    // ---- store: 2 consecutive pixels -> one float2, coalesced ----
    float* onp = out + (size_t)n * (O_OUT * HH * WW);
    const int hB = h0 + rbase;
    const int wcol = w0 + 2 * l;
    float* obase = &onp[((size_t)(og * 2) * HH + hB) * WW + wcol];
    #pragma unroll
    for (int o2 = 0; o2 < 2; ++o2) {
        #pragma unroll
        for (int j = 0; j < 4; ++j) {
            float2 rr = make_float2(acc[o2][j][0], acc[o2][j][1]);
            *(float2*)(obase + (size_t)o2 * (HH * WW) + j * WW) = rr;
        }
    }
}

extern "C" void kernel_launch(void* const* d_in, const int* in_sizes, int n_in,
                              void* d_out, int out_size, void* d_ws, size_t ws_size,
                              hipStream_t stream) {
    const float* x   = (const float*)d_in[0];
    const float* wgt = (const float*)d_in[1];
    float* out = (float*)d_out;

    dim3 grid(WW / TW, HH / TH, 4);   // (4, 64, 4) = 1024 blocks x 512 thr
    dim3 block(512);
    dil_kernel<<<grid, block, 0, stream>>>(x, wgt, out);
}

// Round 19
// 90.253 us; speedup vs baseline: 1.1684x; 1.1684x over previous
//
#include <hip/hip_runtime.h>
#include <math.h>
#include <stdint.h>

#define KK 5
#define PADK 2
#define C_IN 8
#define O_OUT 8
#define HH 512
#define WW 512
#define TH 8
#define TW 128
#define CH 4                      // channels per staged half
#define LROWS 12                  // TH + 4
#define LCOLS 136                 // TW + 4 halo, padded (f32 cols)
#define WSTR 12                   // dwords per (c,og,dy) chunk: 10 used
#define NW (O_OUT * C_IN * KK * KK)   // 1600
#define XHALF (CH * LROWS * (LCOLS / 2))   // float2 slots per half = 3264

// Full-rate VOP3 3-input max.
static __device__ __forceinline__ float max3f(float a, float b, float c) {
    float d;
    asm("v_max3_f32 %0, %1, %2, %3" : "=v"(d) : "v"(a), "v"(b), "v"(c));
    return d;
}

// Packed f32 add with src0-half BROADCAST via VOP3P op_sel (verified exact
// in R18: absmax 0):
//   PK_LO: dst = (x.lo + w.lo, x.lo + w.hi)   -- one tap vs two o's
//   PK_HI: dst = (x.hi + w.lo, x.hi + w.hi)
#define PK_LO(dst, xp, wp)                                                  \
    asm("v_pk_add_f32 %0, %1, %2 op_sel:[0,0] op_sel_hi:[0,1]"              \
        : "=v"(dst) : "v"(xp), "v"(wp))
#define PK_HI(dst, xp, wp)                                                  \
    asm("v_pk_add_f32 %0, %1, %2 op_sel:[1,0] op_sel_hi:[1,1]"              \
        : "=v"(dst) : "v"(xp), "v"(wp))

__global__ __launch_bounds__(512, 6)   // 85-VGPR cap: room for asm temps,
                                       // NO spill (R15/R17/R18 failure mode)
void dil_kernel(const float* __restrict__ x,
                const float* __restrict__ wf,
                float* __restrict__ out) {
    __shared__ __align__(16) float xlds[CH][LROWS][LCOLS];      // 26,112 B
    __shared__ __align__(16) float wlds[C_IN * 4 * KK * WSTR];  //  7,680 B

    const int tid = threadIdx.x;
    const int w0 = blockIdx.x * TW;
    const int h0 = blockIdx.y * TH;
    const int n  = blockIdx.z;
    const float* xn = x + (size_t)n * (C_IN * HH * WW);

    const int l   = tid & 63;
    const int wid = tid >> 6;
    const int og  = wid & 3;
    const int rbase = (wid >> 2) * 4;

    const float* xbase = &xlds[0][rbase][2 * l];
    const float* wog   = wlds + og * (KK * WSTR);

    float acc[2][4][2];           // [o2][j][pixel]
    #pragma unroll
    for (int a = 0; a < 2; ++a)
        #pragma unroll
        for (int j = 0; j < 4; ++j) {
            acc[a][j][0] = -INFINITY;
            acc[a][j][1] = -INFINITY;
        }

    for (int h = 0; h < 2; ++h) {
        if (h) __syncthreads();

        // ---- stage x half (4 channels), zero halo == reference zero pad ----
        for (int idx = tid; idx < XHALF; idx += 512) {
            int cc  = idx / (LROWS * (LCOLS / 2));
            int rem = idx - cc * (LROWS * (LCOLS / 2));
            int r   = rem / (LCOLS / 2);
            int jp  = rem - r * (LCOLS / 2);
            int gh = h0 - PADK + r;
            int gw = w0 - PADK + 2 * jp;
            float v0 = 0.f, v1 = 0.f;
            if ((unsigned)gh < (unsigned)HH) {
                const float* row = xn + ((size_t)(h * CH + cc) * HH + gh) * WW;
                if ((unsigned)gw < (unsigned)WW) v0 = row[gw];
                if ((unsigned)(gw + 1) < (unsigned)WW) v1 = row[gw + 1];
            }
            *(float2*)&xlds[cc][r][2 * jp] = make_float2(v0, v1);
        }
        // ---- stage weights once: [c][g][dy] -> 5 dx-major o-PAIRS ----
        if (h == 0) {
            for (int t = tid; t < NW; t += 512) {
                int dx = t % KK;  int q = t / KK;
                int o2 = q & 1;   q >>= 1;
                int dy = q % KK;  q /= KK;
                int g  = q & 3;   int c = q >> 2;
                int o = g * 2 + o2;
                wlds[((c * 4 + g) * KK + dy) * WSTR + dx * 2 + o2] =
                    wf[((o * C_IN + c) * KK + dy) * KK + dx];
            }
        }
        __syncthreads();

        const float* wh = wog + h * (CH * 4 * KK * WSTR);

        #pragma unroll
        for (int cc = 0; cc < CH; ++cc) {
            #pragma unroll
            for (int dy = 0; dy < KK; ++dy) {
                const float* wch = wh + (cc * 4 * KK + dy) * WSTR;
                float4 wa = *(const float4*)(wch);      // W0=(x,y) W1=(z,w)
                float4 wb = *(const float4*)(wch + 4);  // W2=(x,y) W3=(z,w)
                float2 W4 = *(const float2*)(wch + 8);
                float2 W0 = make_float2(wa.x, wa.y);
                float2 W1 = make_float2(wa.z, wa.w);
                float2 W2 = make_float2(wb.x, wb.y);
                float2 W3 = make_float2(wb.z, wb.w);
                #pragma unroll
                for (int j = 0; j < 4; ++j) {
                    const float* lr = xbase + cc * (LROWS * LCOLS)
                                            + (dy + j) * LCOLS;
                    float2 A = *(const float2*)(lr);        // (u0,u1)
                    float2 B = *(const float2*)(lr + 2);    // (u2,u3)
                    float2 D = *(const float2*)(lr + 4);    // (u4,u5)

                    // pixel 0 taps -> reduce -> temps die before pixel 1
                    float2 T0, T1, T2, T3, T4;
                    PK_LO(T0, A, W0);            // u0 + (wA0,wB0)
                    PK_HI(T1, A, W1);            // u1 + (wA1,wB1)
                    PK_LO(T2, B, W2);            // u2
                    PK_HI(T3, B, W3);            // u3
                    PK_LO(T4, D, W4);            // u4
                    acc[0][j][0] = max3f(acc[0][j][0],
                                         max3f(T0.x, T1.x, T2.x),
                                         fmaxf(T3.x, T4.x));
                    acc[1][j][0] = max3f(acc[1][j][0],
                                         max3f(T0.y, T1.y, T2.y),
                                         fmaxf(T3.y, T4.y));

                    // pixel 1 taps (reuse the same 5 temps)
                    PK_HI(T0, A, W0);            // u1
                    PK_LO(T1, B, W1);            // u2
                    PK_HI(T2, B, W2);            // u3
                    PK_LO(T3, D, W3);            // u4
                    PK_HI(T4, D, W4);            // u5
                    acc[0][j][1] = max3f(acc[0][j][1],
                                         max3f(T0.x, T1.x, T2.x),
                                         fmaxf(T3.x, T4.x));
                    acc[1][j][1] = max3f(acc[1][j][1],
                                         max3f(T0.y, T1.y, T2.y),
                                         fmaxf(T3.y, T4.y));
                }
            }
        }
    }

    // ---- store: 2 consecutive pixels -> one float2, coalesced ----
    float* onp = out + (size_t)n * (O_OUT * HH * WW);
    const int hB = h0 + rbase;
    const int wcol = w0 + 2 * l;
    float* obase = &onp[((size_t)(og * 2) * HH + hB) * WW + wcol];
    #pragma unroll
    for (int o2 = 0; o2 < 2; ++o2) {
        #pragma unroll
        for (int j = 0; j < 4; ++j) {
            float2 rr = make_float2(acc[o2][j][0], acc[o2][j][1]);
            *(float2*)(obase + (size_t)o2 * (HH * WW) + j * WW) = rr;
        }
    }
}

extern "C" void kernel_launch(void* const* d_in, const int* in_sizes, int n_in,
                              void* d_out, int out_size, void* d_ws, size_t ws_size,
                              hipStream_t stream) {
    const float* x   = (const float*)d_in[0];
    const float* wgt = (const float*)d_in[1];
    float* out = (float*)d_out;

    dim3 grid(WW / TW, HH / TH, 4);   // (4, 64, 4) = 1024 blocks x 512 thr
    dim3 block(512);
    dil_kernel<<<grid, block, 0, stream>>>(x, wgt, out);
}